// Round 8
// baseline (221.113 us; speedup 1.0000x reference)
//
#include <hip/hip_runtime.h>
#include <hip/hip_cooperative_groups.h>
#include <hip/hip_bf16.h>
#include <stdint.h>

namespace cg = cooperative_groups;

// Problem constants (static graph layout)
#define NB 64
#define NN 4096
#define NS 512
#define NC 128
#define NTOTAL (NB*NN)          // 262144
#define NE 4194304
#define KSENT 3
#define KOTHER 1792
#define KPG (KSENT+KOTHER)      // 1795
#define NP (NB*KPG)             // 114880
#define NSENT_TOT (NB*KSENT)    // 192
#define NOTHER (NN-NS)          // 3584

// d_out element offsets (f32 elements), concatenated flat in return order:
// x_out[114880,128], edge_index_new[2,E], batch_out[P], perm[P], score[P], num_edges[1]
#define OFF_X     0ull
#define OFF_EDGE  14704640ull
#define OFF_BATCH 23093248ull
#define OFF_PERM  23208128ull
#define OFF_SCORE 23323008ull
#define OFF_NE    23437888ull

#define NEBLK 512               // edge blocks == cooperative grid size
#define EPB   (NE/NEBLK)        // 8192 edges per block
#define STASH 2560              // kept/block: mean 1575, sd 36 -> +27 sigma
#define NBW   (NTOTAL/32)       // 8192 bitmap words

#define FLG_AGG (1ull<<62)
#define FLG_INC (2ull<<62)

// Module-scope scratch. ~2.5 MB.
__device__ float g_scores[NTOTAL];
__device__ int   g_perm[NP];
__device__ int   g_nodemap[NTOTAL];
__device__ uint32_t g_bits[NBW];               // kept-node bitmap
__device__ unsigned long long g_state[NEBLK];  // lookback: flag(2b)|value(32b)

// f32 -> bf16 RNE, kept as f32. Ref is bf16-rounded.
__device__ __forceinline__ float bfr(float f){
  uint32_t u = __float_as_uint(f);
  uint32_t r = u + 0x7FFFu + ((u >> 16) & 1u);
  return __uint_as_float(r & 0xFFFF0000u);
}

// Bit-exact XLA:CPU EmitTanh (f32). Passing R2-R7.
__device__ __forceinline__ float xla_tanhf(float x){
#pragma clang fp contract(off)
  float xc = fminf(fmaxf(x, -7.90531110763549805f), 7.90531110763549805f);
  float x2 = __fmul_rn(xc, xc);
  float p = -2.76076847742355e-16f;
  p = __fadd_rn(__fmul_rn(p, x2),  2.00018790482477e-13f);
  p = __fadd_rn(__fmul_rn(p, x2), -8.60467152213735e-11f);
  p = __fadd_rn(__fmul_rn(p, x2),  5.12229709037114e-08f);
  p = __fadd_rn(__fmul_rn(p, x2),  1.48572235717979e-05f);
  p = __fadd_rn(__fmul_rn(p, x2),  6.37261928875436e-04f);
  p = __fadd_rn(__fmul_rn(p, x2),  4.89352455891786e-03f);
  p = __fmul_rn(xc, p);
  float q = 1.19825839466702e-06f;
  q = __fadd_rn(__fmul_rn(q, x2), 1.18534705686654e-04f);
  q = __fadd_rn(__fmul_rn(q, x2), 2.26843463243900e-03f);
  q = __fadd_rn(__fmul_rn(q, x2), 4.89352518554385e-03f);
  float r = __fdiv_rn(p, q);
  return (fabsf(x) < 0.0004f) ? x : r;
}

__device__ __forceinline__ unsigned long long skey(float s, int idx){
  uint32_t u = __float_as_uint(s);
  u = (u & 0x80000000u) ? ~u : (u | 0x80000000u);
  u = ~u;
  return ((unsigned long long)u << 32) | (uint32_t)idx;
}

// Cooperative mega-kernel: 512 blocks x 512 thr, all co-resident (2/CU).
// P1 scores -> grid.sync -> P2 topk(64 blocks) -> grid.sync -> P3 edges -> P4 gather.
__global__ __launch_bounds__(512) void mega(const float* __restrict__ x,
                                            const float* __restrict__ w,
                                            const int* __restrict__ ei,
                                            float* __restrict__ out){
  // 55.9 KB shared buffer, carved per phase (topk 55.9 KB / edges 52.1 KB)
  __shared__ __align__(16) char smem[55936];
  cg::grid_group grid = cg::this_grid();
  int b = blockIdx.x, tid = threadIdx.x;
  int lane = tid & 63, wvid = tid >> 6;

  // ---- Phase 0: init ----
  if (tid == 0) g_state[b] = 0ull;          // re-arm lookback for this call
  g_nodemap[b*512 + tid] = -1;              // 512*512 == NTOTAL exactly

  // ---- Phase 1: scores (bit-identical chains: R5/R6-producer, passed) ----
  {
#pragma clang fp contract(off)
    int grp = tid >> 4, j = tid & 15;
    float wvv[8];
#pragma unroll
    for (int k = 0; k < 8; ++k) wvv[k] = w[k*16 + j];

    float an = 0.f;
#pragma unroll
    for (int k = 0; k < 8; ++k) an = __fadd_rn(an, __fmul_rn(wvv[k], wvv[k]));
    float o;
    o = __shfl_down(an, 8); if (j < 8) an = __fadd_rn(an, o);
    o = __shfl_down(an, 4); if (j < 4) an = __fadd_rn(an, o);
    o = __shfl_down(an, 2); if (j < 2) an = __fadd_rn(an, o);
    o = __shfl_down(an, 1);
    float nrm = __fsqrt_rn(__fadd_rn(an, o));   // valid at j==0

#pragma unroll 2
    for (int it = 0; it < 16; ++it){
      int row = it*16384 + b*32 + grp;
      const float* rx = x + (size_t)row*NC;
      float ad = 0.f;
#pragma unroll
      for (int k = 0; k < 8; ++k)
        ad = __fadd_rn(ad, __fmul_rn(rx[k*16 + j], wvv[k]));
      o = __shfl_down(ad, 8); if (j < 8) ad = __fadd_rn(ad, o);
      o = __shfl_down(ad, 4); if (j < 4) ad = __fadd_rn(ad, o);
      o = __shfl_down(ad, 2); if (j < 2) ad = __fadd_rn(ad, o);
      o = __shfl_down(ad, 1);
      if (j == 0){
        float t = __fdiv_rn(__fadd_rn(ad, o), nrm);
        g_scores[row] = xla_tanhf(t);
      }
    }
  }
  grid.sync();

  // ---- Phase 2: topk for graph b (blocks 0..63); R5 body, smem-carved ----
  if (b < NB){
    uint32_t* keyA = (uint32_t*)(smem);
    uint32_t* keyB = (uint32_t*)(smem + 14336);
    uint16_t* idxA = (uint16_t*)(smem + 28672);
    uint16_t* idxB = (uint16_t*)(smem + 35840);
    uint16_t* rnk  = (uint16_t*)(smem + 43008);
    uint16_t (*cnt)[256] = (uint16_t(*)[256])(smem + 50176);
    uint16_t* totA  = (uint16_t*)(smem + 54272);
    uint16_t* dbase = (uint16_t*)(smem + 54784);
    unsigned long long* smin = (unsigned long long*)(smem + 55296);
    unsigned long long* swin = (unsigned long long*)(smem + 55360);
    uint32_t* bl = (uint32_t*)(smem + 55376);   // 128 words

    int g = b;
    const float* sg = g_scores + g*NN;

    if (tid < NN/32) bl[tid] = 0u;
    __syncthreads();

    unsigned long long key = skey(sg[tid], tid);
    for (int t = 0; t < KSENT; ++t){
      unsigned long long v = key;
#pragma unroll
      for (int off = 32; off; off >>= 1){
        unsigned long long o = __shfl_down(v, off);
        v = (o < v) ? o : v;
      }
      if (lane == 0) smin[wvid] = v;
      __syncthreads();
      if (tid == 0){
        unsigned long long mm = smin[0];
        for (int w2 = 1; w2 < 8; ++w2) if (smin[w2] < mm) mm = smin[w2];
        *swin = mm;
      }
      __syncthreads();
      unsigned long long winner = *swin;
      if (key == winner){
        int idx = (int)(winner & 0xFFFFFFFFull);
        int node = g*NN + idx, p = g*KSENT + t;
        g_perm[p] = node;
        g_nodemap[node] = p;
        atomicOr(&bl[idx >> 5], 1u << (idx & 31));
        key = ~0ull;
      }
      __syncthreads();
    }

    for (int i = tid; i < NOTHER; i += 512){
      uint32_t u = __float_as_uint(sg[NS + i]);
      u = (u & 0x80000000u) ? ~u : (u | 0x80000000u);
      keyA[i] = ~u;
      idxA[i] = (uint16_t)i;
    }
    __syncthreads();

    uint32_t* ksrc = keyA; uint32_t* kdst = keyB;
    uint16_t* isrc = idxA; uint16_t* idst = idxB;
    unsigned long long ltmask = (1ull << lane) - 1ull;
    int base = wvid * 448;

    for (int pass = 0; pass < 4; ++pass){
      int shift = pass * 8;
      uint32_t* c32 = (uint32_t*)cnt[wvid];
      c32[lane] = 0; c32[64 + lane] = 0;
      for (int r = 0; r < 7; ++r){
        int i = base + r*64 + lane;
        uint32_t k = ksrc[i];
        uint32_t d = (k >> shift) & 255u;
        unsigned long long m = ~0ull;
#pragma unroll
        for (int bb = 0; bb < 8; ++bb){
          unsigned long long bm2 = __ballot((d >> bb) & 1u);
          m &= ((d >> bb) & 1u) ? bm2 : ~bm2;
        }
        int rir = __popcll(m & ltmask);
        uint16_t bse = cnt[wvid][d];
        rnk[i] = (uint16_t)(bse + rir);
        if ((m >> lane) == 1ull)
          cnt[wvid][d] = (uint16_t)(bse + __popcll(m));
      }
      __syncthreads();
      if (tid < 256){
        int s = 0;
#pragma unroll
        for (int w2 = 0; w2 < 8; ++w2){
          int t2 = cnt[w2][tid]; cnt[w2][tid] = (uint16_t)s; s += t2;
        }
        totA[tid] = (uint16_t)s;
      }
      __syncthreads();
      if (tid < 64){
        int b4 = tid*4;
        int s0=totA[b4], s1=totA[b4+1], s2=totA[b4+2], s3=totA[b4+3];
        int lsum = s0+s1+s2+s3;
        int sc = lsum;
        for (int off = 1; off < 64; off <<= 1){
          int vv = __shfl_up(sc, off);
          if (lane >= off) sc += vv;
        }
        int excl = sc - lsum;
        dbase[b4]   = (uint16_t)excl;
        dbase[b4+1] = (uint16_t)(excl + s0);
        dbase[b4+2] = (uint16_t)(excl + s0 + s1);
        dbase[b4+3] = (uint16_t)(excl + s0 + s1 + s2);
      }
      __syncthreads();
      {
        int idx = tid;
#pragma unroll
        for (int kk = 0; kk < 4; ++kk){
          int w2 = (idx >> 8) & 7, d2 = idx & 255;
          cnt[w2][d2] = (uint16_t)(cnt[w2][d2] + dbase[d2]);
          idx += 512;
        }
      }
      __syncthreads();
      for (int r = 0; r < 7; ++r){
        int i = base + r*64 + lane;
        uint32_t k = ksrc[i];
        uint32_t d = (k >> shift) & 255u;
        int dest = cnt[wvid][d] + rnk[i];
        kdst[dest] = k; idst[dest] = isrc[i];
      }
      __syncthreads();
      uint32_t* tk = ksrc; ksrc = kdst; kdst = tk;
      uint16_t* ti = isrc; isrc = idst; idst = ti;
    }
    for (int j = tid; j < KOTHER; j += 512){
      int li = NS + (int)isrc[j];
      int node = g*NN + li;
      int p = NSENT_TOT + g*KOTHER + j;
      g_perm[p] = node;
      g_nodemap[node] = p;
      atomicOr(&bl[li >> 5], 1u << (li & 31));
    }
    __syncthreads();
    if (tid < NN/32) g_bits[g*(NN/32) + tid] = bl[tid];
  }
  grid.sync();

  // ---- Phase 3: edges (all 512 blocks); R6/R7 body, smem-carved ----
  {
    uint32_t* bm  = (uint32_t*)(smem);          // 32 KB
    int2* rc      = (int2*)(smem + 32768);      // 20 KB
    int* wsum     = (int*)(smem + 53248);       // 8 ints
    int* s_off    = (int*)(smem + 53280);

    int base = b * EPB;
    unsigned long long ltm = (1ull << lane) - 1ull;

    { // stage bitmap: 8192 words / 512 thr = 4 x dwordx4
      uint4* d4 = (uint4*)bm;
      const uint4* s4 = (const uint4*)g_bits;
#pragma unroll
      for (int kk = 0; kk < 4; ++kk) d4[tid + kk*512] = s4[tid + kk*512];
    }
    if (tid == 0) *s_off = 0;
    __syncthreads();

    // Phase A: keep flags from LDS bitmap, stable local positions, stash
    int running = 0;
    for (int s = 0; s < EPB; s += 512){
      int e = base + s + tid;
      int u = ei[e], v = ei[NE + e];
      bool keep = ((bm[u >> 5] >> (u & 31)) & 1u) &&
                  ((bm[v >> 5] >> (v & 31)) & 1u);
      unsigned long long m = __ballot(keep);
      if (lane == 0) wsum[wvid] = __popcll(m);
      __syncthreads();
      int wbase = 0;
#pragma unroll
      for (int w2 = 0; w2 < 8; ++w2) if (w2 < wvid) wbase += wsum[w2];
      int tot = 0;
#pragma unroll
      for (int w2 = 0; w2 < 8; ++w2) tot += wsum[w2];
      if (keep){
        int lp = running + wbase + __popcll(m & ltm);
        if (lp < STASH){
          int2 p; p.x = g_nodemap[u]; p.y = g_nodemap[v]; rc[lp] = p;
        }
      }
      running += tot;
      __syncthreads();
    }
    int myc = running;

    // Phase B: decoupled lookback (wave 0) — R4-R7 (passed)
    if (b == 0){
      if (tid == 0)
        atomicExch(&g_state[0], FLG_INC | (unsigned long long)(uint32_t)myc);
    } else if (wvid == 0){
      if (lane == 0)
        atomicExch(&g_state[b], FLG_AGG | (unsigned long long)(uint32_t)myc);
      int prev = 0, win = b - 1;
      bool done = false;
      while (!done){
        int idxl = win - lane;
        unsigned long long st = (idxl >= 0) ? atomicAdd(&g_state[idxl], 0ull)
                                            : FLG_INC;
        unsigned f = (unsigned)(st >> 62);
        unsigned long long readym = __ballot(f != 0u);
        unsigned long long incm   = __ballot(f == 2u);
        if (incm){
          int l0 = __ffsll((long long)incm) - 1;
          unsigned long long needm = (l0 == 63) ? ~0ull : ((1ull << (l0+1)) - 1ull);
          if ((readym & needm) == needm){
            int contrib = (lane <= l0) ? (int)(uint32_t)st : 0;
#pragma unroll
            for (int off = 32; off; off >>= 1)
              contrib += __shfl_down(contrib, off);
            if (lane == 0) prev += contrib;
            done = true;
          }
        } else if (readym == ~0ull){
          int contrib = (int)(uint32_t)st;
#pragma unroll
          for (int off = 32; off; off >>= 1)
            contrib += __shfl_down(contrib, off);
          if (lane == 0) prev += contrib;
          win -= 64;
        } else {
          __builtin_amdgcn_s_sleep(2);
        }
      }
      if (lane == 0){
        atomicExch(&g_state[b], FLG_INC | (unsigned long long)(uint32_t)(prev + myc));
        *s_off = prev;
        if (b == NEBLK-1)
          out[OFF_NE] = bfr((float)(prev + myc));
      }
    }
    __syncthreads();
    int off = *s_off;

    // Phase C: write kept edges from stash (coalesced)
    int lim = myc < STASH ? myc : STASH;
    for (int i = tid; i < lim; i += 512){
      int2 p = rc[i];
      out[OFF_EDGE + off + i]      = bfr((float)p.x);
      out[OFF_EDGE + NE + off + i] = bfr((float)p.y);
    }
    // Rare fallback: stash overflow -> recompute positions
    if (myc > STASH){
      running = 0;
      __syncthreads();
      for (int s = 0; s < EPB; s += 512){
        int e = base + s + tid;
        int u = ei[e], v = ei[NE + e];
        bool keep = ((bm[u >> 5] >> (u & 31)) & 1u) &&
                    ((bm[v >> 5] >> (v & 31)) & 1u);
        unsigned long long m = __ballot(keep);
        if (lane == 0) wsum[wvid] = __popcll(m);
        __syncthreads();
        int wbase = 0;
#pragma unroll
        for (int w2 = 0; w2 < 8; ++w2) if (w2 < wvid) wbase += wsum[w2];
        int tot = 0;
#pragma unroll
        for (int w2 = 0; w2 < 8; ++w2) tot += wsum[w2];
        if (keep){
          int lp = running + wbase + __popcll(m & ltm);
          if (lp >= STASH){
            out[OFF_EDGE + off + lp]      = bfr((float)g_nodemap[u]);
            out[OFF_EDGE + NE + off + lp] = bfr((float)g_nodemap[v]);
          }
        }
        running += tot;
        __syncthreads();
      }
    }

    // Tail drop-slice: block b fills [NE - dropoff - drops, NE - dropoff)
    int drops = EPB - myc;
    int dropoff = base - off;
    int t0 = NE - dropoff - drops;
    for (int i = tid; i < drops; i += 512){
      out[OFF_EDGE + t0 + i]      = -1.0f;
      out[OFF_EDGE + NE + t0 + i] = -1.0f;
    }
  }

  // ---- Phase 4: gather grid-stride (no barrier needed; deps sync'd at P2) ----
  {
    const size_t total4 = (size_t)NP*NC/4;   // 3,676,160
    for (size_t q = (size_t)b*512 + tid; q < total4; q += (size_t)NEBLK*512){
      int p  = (int)(q >> 5);
      int c4 = (int)(q & 31);
      int node = g_perm[p];
      float s = g_scores[node];
      float4 v = *(const float4*)(x + (size_t)node*NC + c4*4);
      float4 o;
      o.x = bfr(__fmul_rn(v.x, s));
      o.y = bfr(__fmul_rn(v.y, s));
      o.z = bfr(__fmul_rn(v.z, s));
      o.w = bfr(__fmul_rn(v.w, s));
      *(float4*)(out + OFF_X + (size_t)p*NC + c4*4) = o;
      if (c4 == 0){
        out[OFF_BATCH + p] = bfr((float)(node >> 12));
        out[OFF_PERM  + p] = bfr((float)node);
        out[OFF_SCORE + p] = bfr(s);
      }
    }
  }
}

extern "C" void kernel_launch(void* const* d_in, const int* in_sizes, int n_in,
                              void* d_out, int out_size, void* d_ws, size_t ws_size,
                              hipStream_t stream) {
  const float* x = (const float*)d_in[0];
  const float* w = (const float*)d_in[1];
  const int*   ei = (const int*)d_in[2];
  float* out = (float*)d_out;

  void* args[4] = {(void*)&x, (void*)&w, (void*)&ei, (void*)&out};
  hipLaunchCooperativeKernel((const void*)mega, dim3(NEBLK), dim3(512),
                             args, 0, stream);
}

// Round 9
// 202.174 us; speedup vs baseline: 1.0937x; 1.0937x over previous
//
#include <hip/hip_runtime.h>
#include <hip/hip_bf16.h>
#include <stdint.h>

// Problem constants (static graph layout)
#define NB 64
#define NN 4096
#define NS 512
#define NC 128
#define NTOTAL (NB*NN)          // 262144
#define NE 4194304
#define KSENT 3
#define KOTHER 1792
#define KPG (KSENT+KOTHER)      // 1795
#define NP (NB*KPG)             // 114880
#define NSENT_TOT (NB*KSENT)    // 192
#define NOTHER (NN-NS)          // 3584

// d_out element offsets (f32 elements), concatenated flat in return order:
// x_out[114880,128], edge_index_new[2,E], batch_out[P], perm[P], score[P], num_edges[1]
#define OFF_X     0ull
#define OFF_EDGE  14704640ull
#define OFF_BATCH 23093248ull
#define OFF_PERM  23208128ull
#define OFF_SCORE 23323008ull
#define OFF_NE    23437888ull

#define NEBLK 512               // edge blocks
#define EPB   (NE/NEBLK)        // 8192 edges per block
#define STASH 2560              // kept/block: mean 1575, sd 36 -> +27 sigma
#define NGB   1024              // gather blocks
#define NBW   (NTOTAL/32)       // 8192 bitmap words

#define FLG_AGG (1ull<<62)
#define FLG_INC (2ull<<62)

// Module-scope scratch. ~2.5 MB.
__device__ float g_scores[NTOTAL];
__device__ int   g_perm[NP];
__device__ int   g_nodemap[NTOTAL];
__device__ uint32_t g_bits[NBW];               // kept-node bitmap
__device__ unsigned long long g_state[NEBLK];  // lookback: flag(2b)|value(32b)
__device__ int   g_done[NB];                   // per-graph finish counters (self-re-arming)

// f32 -> bf16 RNE, kept as f32. Ref is bf16-rounded.
__device__ __forceinline__ float bfr(float f){
  uint32_t u = __float_as_uint(f);
  uint32_t r = u + 0x7FFFu + ((u >> 16) & 1u);
  return __uint_as_float(r & 0xFFFF0000u);
}

// Bit-exact XLA:CPU EmitTanh (f32). Passing R2-R8.
__device__ __forceinline__ float xla_tanhf(float x){
#pragma clang fp contract(off)
  float xc = fminf(fmaxf(x, -7.90531110763549805f), 7.90531110763549805f);
  float x2 = __fmul_rn(xc, xc);
  float p = -2.76076847742355e-16f;
  p = __fadd_rn(__fmul_rn(p, x2),  2.00018790482477e-13f);
  p = __fadd_rn(__fmul_rn(p, x2), -8.60467152213735e-11f);
  p = __fadd_rn(__fmul_rn(p, x2),  5.12229709037114e-08f);
  p = __fadd_rn(__fmul_rn(p, x2),  1.48572235717979e-05f);
  p = __fadd_rn(__fmul_rn(p, x2),  6.37261928875436e-04f);
  p = __fadd_rn(__fmul_rn(p, x2),  4.89352455891786e-03f);
  p = __fmul_rn(xc, p);
  float q = 1.19825839466702e-06f;
  q = __fadd_rn(__fmul_rn(q, x2), 1.18534705686654e-04f);
  q = __fadd_rn(__fmul_rn(q, x2), 2.26843463243900e-03f);
  q = __fadd_rn(__fmul_rn(q, x2), 4.89352518554385e-03f);
  float r = __fdiv_rn(p, q);
  return (fabsf(x) < 0.0004f) ? x : r;
}

__device__ __forceinline__ unsigned long long skey(float s, int idx){
  uint32_t u = __float_as_uint(s);
  u = (u & 0x80000000u) ? ~u : (u | 0x80000000u);
  u = ~u;
  return ((unsigned long long)u << 32) | (uint32_t)idx;
}

// kA: 512 blocks x 512 thr, all co-resident (56KB LDS -> 2/CU x 256 = 512).
// Block b: scores for rows [b*512, (b+1)*512) (graph g = b>>3), then one
// ACQ_REL counter add; the 8th finisher of each graph runs that graph's topk
// (R8-validated carved body). No spinning, no global barrier.
__global__ __launch_bounds__(512) void kA(const float* __restrict__ x,
                                          const float* __restrict__ w){
  __shared__ __align__(16) char smem[55936];
  __shared__ int s_run;
  int b = blockIdx.x, tid = threadIdx.x;
  int lane = tid & 63, wvid = tid >> 6;

  if (tid == 0) g_state[b] = 0ull;          // re-arm k2 lookback
  g_nodemap[b*512 + tid] = -1;              // own rows' nodemap init

  // ---- scores (bit-identical chains: R6-producer, passed) ----
  {
#pragma clang fp contract(off)
    int grp = tid >> 4, j = tid & 15;
    float wvv[8];
#pragma unroll
    for (int k = 0; k < 8; ++k) wvv[k] = w[k*16 + j];

    float an = 0.f;
#pragma unroll
    for (int k = 0; k < 8; ++k) an = __fadd_rn(an, __fmul_rn(wvv[k], wvv[k]));
    float o;
    o = __shfl_down(an, 8); if (j < 8) an = __fadd_rn(an, o);
    o = __shfl_down(an, 4); if (j < 4) an = __fadd_rn(an, o);
    o = __shfl_down(an, 2); if (j < 2) an = __fadd_rn(an, o);
    o = __shfl_down(an, 1);
    float nrm = __fsqrt_rn(__fadd_rn(an, o));   // valid at j==0

    int row0 = b * 512;
    for (int it = 0; it < 16; ++it){
      int row = row0 + it*32 + grp;
      const float* rx = x + (size_t)row*NC;
      float ad = 0.f;
#pragma unroll
      for (int k = 0; k < 8; ++k)
        ad = __fadd_rn(ad, __fmul_rn(rx[k*16 + j], wvv[k]));
      o = __shfl_down(ad, 8); if (j < 8) ad = __fadd_rn(ad, o);
      o = __shfl_down(ad, 4); if (j < 4) ad = __fadd_rn(ad, o);
      o = __shfl_down(ad, 2); if (j < 2) ad = __fadd_rn(ad, o);
      o = __shfl_down(ad, 1);
      if (j == 0){
        float t = __fdiv_rn(__fadd_rn(ad, o), nrm);
        g_scores[row] = xla_tanhf(t);
      }
    }
  }

  // ---- last-finisher handoff (no waiting) ----
  __threadfence();
  __syncthreads();
  int g = b >> 3;
  if (tid == 0){
    int old = __hip_atomic_fetch_add(&g_done[g], 1, __ATOMIC_ACQ_REL,
                                     __HIP_MEMORY_SCOPE_AGENT);
    s_run = (old == 7);
    if (old == 7)
      __hip_atomic_store(&g_done[g], 0, __ATOMIC_RELAXED,
                         __HIP_MEMORY_SCOPE_AGENT);   // re-arm for next call
  }
  __syncthreads();
  if (!s_run) return;

  // ---- topk for graph g (R8-validated carved body) ----
  uint32_t* keyA = (uint32_t*)(smem);
  uint32_t* keyB = (uint32_t*)(smem + 14336);
  uint16_t* idxA = (uint16_t*)(smem + 28672);
  uint16_t* idxB = (uint16_t*)(smem + 35840);
  uint16_t* rnk  = (uint16_t*)(smem + 43008);
  uint16_t (*cnt)[256] = (uint16_t(*)[256])(smem + 50176);
  uint16_t* totA  = (uint16_t*)(smem + 54272);
  uint16_t* dbase = (uint16_t*)(smem + 54784);
  unsigned long long* smin = (unsigned long long*)(smem + 55296);
  unsigned long long* swin = (unsigned long long*)(smem + 55360);
  uint32_t* bl = (uint32_t*)(smem + 55376);   // 128 words

  const float* sg = g_scores + g*NN;

  if (tid < NN/32) bl[tid] = 0u;
  __syncthreads();

  unsigned long long key = skey(sg[tid], tid);
  for (int t = 0; t < KSENT; ++t){
    unsigned long long v = key;
#pragma unroll
    for (int off = 32; off; off >>= 1){
      unsigned long long o = __shfl_down(v, off);
      v = (o < v) ? o : v;
    }
    if (lane == 0) smin[wvid] = v;
    __syncthreads();
    if (tid == 0){
      unsigned long long mm = smin[0];
      for (int w2 = 1; w2 < 8; ++w2) if (smin[w2] < mm) mm = smin[w2];
      *swin = mm;
    }
    __syncthreads();
    unsigned long long winner = *swin;
    if (key == winner){
      int idx = (int)(winner & 0xFFFFFFFFull);
      int node = g*NN + idx, p = g*KSENT + t;
      g_perm[p] = node;
      g_nodemap[node] = p;
      atomicOr(&bl[idx >> 5], 1u << (idx & 31));
      key = ~0ull;
    }
    __syncthreads();
  }

  for (int i = tid; i < NOTHER; i += 512){
    uint32_t u = __float_as_uint(sg[NS + i]);
    u = (u & 0x80000000u) ? ~u : (u | 0x80000000u);
    keyA[i] = ~u;
    idxA[i] = (uint16_t)i;
  }
  __syncthreads();

  uint32_t* ksrc = keyA; uint32_t* kdst = keyB;
  uint16_t* isrc = idxA; uint16_t* idst = idxB;
  unsigned long long ltmask = (1ull << lane) - 1ull;
  int base = wvid * 448;

  for (int pass = 0; pass < 4; ++pass){
    int shift = pass * 8;
    uint32_t* c32 = (uint32_t*)cnt[wvid];
    c32[lane] = 0; c32[64 + lane] = 0;
    for (int r = 0; r < 7; ++r){
      int i = base + r*64 + lane;
      uint32_t k = ksrc[i];
      uint32_t d = (k >> shift) & 255u;
      unsigned long long m = ~0ull;
#pragma unroll
      for (int bb = 0; bb < 8; ++bb){
        unsigned long long bm2 = __ballot((d >> bb) & 1u);
        m &= ((d >> bb) & 1u) ? bm2 : ~bm2;
      }
      int rir = __popcll(m & ltmask);
      uint16_t bse = cnt[wvid][d];
      rnk[i] = (uint16_t)(bse + rir);
      if ((m >> lane) == 1ull)
        cnt[wvid][d] = (uint16_t)(bse + __popcll(m));
    }
    __syncthreads();
    if (tid < 256){
      int s = 0;
#pragma unroll
      for (int w2 = 0; w2 < 8; ++w2){
        int t2 = cnt[w2][tid]; cnt[w2][tid] = (uint16_t)s; s += t2;
      }
      totA[tid] = (uint16_t)s;
    }
    __syncthreads();
    if (tid < 64){
      int b4 = tid*4;
      int s0=totA[b4], s1=totA[b4+1], s2=totA[b4+2], s3=totA[b4+3];
      int lsum = s0+s1+s2+s3;
      int sc = lsum;
      for (int off = 1; off < 64; off <<= 1){
        int vv = __shfl_up(sc, off);
        if (lane >= off) sc += vv;
      }
      int excl = sc - lsum;
      dbase[b4]   = (uint16_t)excl;
      dbase[b4+1] = (uint16_t)(excl + s0);
      dbase[b4+2] = (uint16_t)(excl + s0 + s1);
      dbase[b4+3] = (uint16_t)(excl + s0 + s1 + s2);
    }
    __syncthreads();
    {
      int idx = tid;
#pragma unroll
      for (int kk = 0; kk < 4; ++kk){
        int w2 = (idx >> 8) & 7, d2 = idx & 255;
        cnt[w2][d2] = (uint16_t)(cnt[w2][d2] + dbase[d2]);
        idx += 512;
      }
    }
    __syncthreads();
    for (int r = 0; r < 7; ++r){
      int i = base + r*64 + lane;
      uint32_t k = ksrc[i];
      uint32_t d = (k >> shift) & 255u;
      int dest = cnt[wvid][d] + rnk[i];
      kdst[dest] = k; idst[dest] = isrc[i];
    }
    __syncthreads();
    uint32_t* tk = ksrc; ksrc = kdst; kdst = tk;
    uint16_t* ti = isrc; isrc = idst; idst = ti;
  }
  for (int j = tid; j < KOTHER; j += 512){
    int li = NS + (int)isrc[j];
    int node = g*NN + li;
    int p = NSENT_TOT + g*KOTHER + j;
    g_perm[p] = node;
    g_nodemap[node] = p;
    atomicOr(&bl[li >> 5], 1u << (li & 31));
  }
  __syncthreads();
  if (tid < NN/32) g_bits[g*(NN/32) + tid] = bl[tid];
}

// k2: blocks 0..511 = edges (bitmap keep-test, lookback compaction,
//     per-block tail drop-slice fill); blocks 512..1535 = gather.
// (R7 verbatim, passed.)
__global__ __launch_bounds__(512) void k2(const int* __restrict__ ei,
                                          const float* __restrict__ x,
                                          float* __restrict__ out){
  __shared__ uint32_t bm[NBW];    // 32 KB
  __shared__ int2 rc[STASH];      // 20 KB
  __shared__ int wsum[8];
  __shared__ int s_off;
  int b = blockIdx.x, tid = threadIdx.x;

  if (b >= NEBLK){
    // ---------------- gather + side outputs ----------------
    const size_t total4 = (size_t)NP*NC/4;
    for (size_t q = (size_t)(b - NEBLK)*512 + tid; q < total4;
         q += (size_t)NGB*512){
      int p  = (int)(q >> 5);
      int c4 = (int)(q & 31);
      int node = g_perm[p];
      float s = g_scores[node];
      float4 v = *(const float4*)(x + (size_t)node*NC + c4*4);
      float4 o;
      o.x = bfr(__fmul_rn(v.x, s));
      o.y = bfr(__fmul_rn(v.y, s));
      o.z = bfr(__fmul_rn(v.z, s));
      o.w = bfr(__fmul_rn(v.w, s));
      *(float4*)(out + OFF_X + (size_t)p*NC + c4*4) = o;
      if (c4 == 0){
        out[OFF_BATCH + p] = bfr((float)(node >> 12));
        out[OFF_PERM  + p] = bfr((float)node);
        out[OFF_SCORE + p] = bfr(s);
      }
    }
    return;
  }

  // ---------------- edges ----------------
  int lane = tid & 63, wid = tid >> 6;
  int base = b * EPB;
  unsigned long long ltm = (1ull << lane) - 1ull;

  { // stage bitmap: 8192 words / 512 thr = 4 x dwordx4
    uint4* d4 = (uint4*)bm;
    const uint4* s4 = (const uint4*)g_bits;
#pragma unroll
    for (int kk = 0; kk < 4; ++kk) d4[tid + kk*512] = s4[tid + kk*512];
  }
  if (tid == 0) s_off = 0;
  __syncthreads();

  // Phase A: keep flags from LDS bitmap, stable local positions, stash
  int running = 0;
  for (int s = 0; s < EPB; s += 512){
    int e = base + s + tid;
    int u = ei[e], v = ei[NE + e];
    bool keep = ((bm[u >> 5] >> (u & 31)) & 1u) &&
                ((bm[v >> 5] >> (v & 31)) & 1u);
    unsigned long long m = __ballot(keep);
    if (lane == 0) wsum[wid] = __popcll(m);
    __syncthreads();
    int wbase = 0;
#pragma unroll
    for (int w2 = 0; w2 < 8; ++w2) if (w2 < wid) wbase += wsum[w2];
    int tot = 0;
#pragma unroll
    for (int w2 = 0; w2 < 8; ++w2) tot += wsum[w2];
    if (keep){
      int lp = running + wbase + __popcll(m & ltm);
      if (lp < STASH){
        int2 p; p.x = g_nodemap[u]; p.y = g_nodemap[v]; rc[lp] = p;
      }
    }
    running += tot;
    __syncthreads();
  }
  int myc = running;

  // Phase B: decoupled lookback (wave 0) — R4-R8 (passed)
  if (b == 0){
    if (tid == 0)
      atomicExch(&g_state[0], FLG_INC | (unsigned long long)(uint32_t)myc);
  } else if (wid == 0){
    if (lane == 0)
      atomicExch(&g_state[b], FLG_AGG | (unsigned long long)(uint32_t)myc);
    int prev = 0, win = b - 1;
    bool done = false;
    while (!done){
      int idxl = win - lane;
      unsigned long long st = (idxl >= 0) ? atomicAdd(&g_state[idxl], 0ull)
                                          : FLG_INC;
      unsigned f = (unsigned)(st >> 62);
      unsigned long long readym = __ballot(f != 0u);
      unsigned long long incm   = __ballot(f == 2u);
      if (incm){
        int l0 = __ffsll((long long)incm) - 1;
        unsigned long long needm = (l0 == 63) ? ~0ull : ((1ull << (l0+1)) - 1ull);
        if ((readym & needm) == needm){
          int contrib = (lane <= l0) ? (int)(uint32_t)st : 0;
#pragma unroll
          for (int off = 32; off; off >>= 1)
            contrib += __shfl_down(contrib, off);
          if (lane == 0) prev += contrib;
          done = true;
        }
      } else if (readym == ~0ull){
        int contrib = (int)(uint32_t)st;
#pragma unroll
        for (int off = 32; off; off >>= 1)
          contrib += __shfl_down(contrib, off);
        if (lane == 0) prev += contrib;
        win -= 64;
      } else {
        __builtin_amdgcn_s_sleep(2);
      }
    }
    if (lane == 0){
      atomicExch(&g_state[b], FLG_INC | (unsigned long long)(uint32_t)(prev + myc));
      s_off = prev;
      if (b == NEBLK-1)
        out[OFF_NE] = bfr((float)(prev + myc));
    }
  }
  __syncthreads();
  int off = s_off;

  // Phase C: write kept edges from stash (coalesced)
  int lim = myc < STASH ? myc : STASH;
  for (int i = tid; i < lim; i += 512){
    int2 p = rc[i];
    out[OFF_EDGE + off + i]      = bfr((float)p.x);
    out[OFF_EDGE + NE + off + i] = bfr((float)p.y);
  }
  // Rare fallback: stash overflow -> recompute positions
  if (myc > STASH){
    running = 0;
    __syncthreads();
    for (int s = 0; s < EPB; s += 512){
      int e = base + s + tid;
      int u = ei[e], v = ei[NE + e];
      bool keep = ((bm[u >> 5] >> (u & 31)) & 1u) &&
                  ((bm[v >> 5] >> (v & 31)) & 1u);
      unsigned long long m = __ballot(keep);
      if (lane == 0) wsum[wid] = __popcll(m);
      __syncthreads();
      int wbase = 0;
#pragma unroll
      for (int w2 = 0; w2 < 8; ++w2) if (w2 < wid) wbase += wsum[w2];
      int tot = 0;
#pragma unroll
      for (int w2 = 0; w2 < 8; ++w2) tot += wsum[w2];
      if (keep){
        int lp = running + wbase + __popcll(m & ltm);
        if (lp >= STASH){
          out[OFF_EDGE + off + lp]      = bfr((float)g_nodemap[u]);
          out[OFF_EDGE + NE + off + lp] = bfr((float)g_nodemap[v]);
        }
      }
      running += tot;
      __syncthreads();
    }
  }

  // Tail drop-slice: block b fills [NE - dropoff - drops, NE - dropoff)
  // with -1 in both rows. Slices tile [T, NE) exactly; values identical.
  int drops = EPB - myc;
  int dropoff = base - off;
  int t0 = NE - dropoff - drops;
  for (int i = tid; i < drops; i += 512){
    out[OFF_EDGE + t0 + i]      = -1.0f;
    out[OFF_EDGE + NE + t0 + i] = -1.0f;
  }
}

extern "C" void kernel_launch(void* const* d_in, const int* in_sizes, int n_in,
                              void* d_out, int out_size, void* d_ws, size_t ws_size,
                              hipStream_t stream) {
  const float* x = (const float*)d_in[0];
  const float* w = (const float*)d_in[1];
  const int*   ei = (const int*)d_in[2];
  float* out = (float*)d_out;

  hipLaunchKernelGGL(kA, dim3(512),         dim3(512), 0, stream, x, w);
  hipLaunchKernelGGL(k2, dim3(NEBLK + NGB), dim3(512), 0, stream, ei, x, out);
}

// Round 10
// 104.711 us; speedup vs baseline: 2.1116x; 1.9308x over previous
//
#include <hip/hip_runtime.h>
#include <hip/hip_bf16.h>
#include <stdint.h>

// Problem constants (static graph layout)
#define NB 64
#define NN 4096
#define NS 512
#define NC 128
#define NTOTAL (NB*NN)          // 262144
#define NE 4194304
#define KSENT 3
#define KOTHER 1792
#define KPG (KSENT+KOTHER)      // 1795
#define NP (NB*KPG)             // 114880
#define NSENT_TOT (NB*KSENT)    // 192
#define NOTHER (NN-NS)          // 3584

// d_out element offsets (f32 elements), concatenated flat in return order:
// x_out[114880,128], edge_index_new[2,E], batch_out[P], perm[P], score[P], num_edges[1]
#define OFF_X     0ull
#define OFF_EDGE  14704640ull
#define OFF_BATCH 23093248ull
#define OFF_PERM  23208128ull
#define OFF_SCORE 23323008ull
#define OFF_NE    23437888ull

#define NEBLK 512               // edge blocks
#define EPB   (NE/NEBLK)        // 8192 edges per block (16 per thread)
#define NGB   1024              // gather blocks
#define NBW   (NTOTAL/32)       // 8192 bitmap words

#define FLG_AGG (1ull<<62)
#define FLG_INC (2ull<<62)

// Module-scope scratch. ~2.5 MB.
__device__ float g_scores[NTOTAL];
__device__ int   g_perm[NP];
__device__ int   g_nodemap[NTOTAL];
__device__ uint32_t g_bits[NBW];               // kept-node bitmap
__device__ unsigned long long g_state[NEBLK];  // lookback: flag(2b)|value(32b)

// f32 -> bf16 RNE, kept as f32. Ref is bf16-rounded.
__device__ __forceinline__ float bfr(float f){
  uint32_t u = __float_as_uint(f);
  uint32_t r = u + 0x7FFFu + ((u >> 16) & 1u);
  return __uint_as_float(r & 0xFFFF0000u);
}

// Bit-exact XLA:CPU EmitTanh (f32). Passing R2-R9.
__device__ __forceinline__ float xla_tanhf(float x){
#pragma clang fp contract(off)
  float xc = fminf(fmaxf(x, -7.90531110763549805f), 7.90531110763549805f);
  float x2 = __fmul_rn(xc, xc);
  float p = -2.76076847742355e-16f;
  p = __fadd_rn(__fmul_rn(p, x2),  2.00018790482477e-13f);
  p = __fadd_rn(__fmul_rn(p, x2), -8.60467152213735e-11f);
  p = __fadd_rn(__fmul_rn(p, x2),  5.12229709037114e-08f);
  p = __fadd_rn(__fmul_rn(p, x2),  1.48572235717979e-05f);
  p = __fadd_rn(__fmul_rn(p, x2),  6.37261928875436e-04f);
  p = __fadd_rn(__fmul_rn(p, x2),  4.89352455891786e-03f);
  p = __fmul_rn(xc, p);
  float q = 1.19825839466702e-06f;
  q = __fadd_rn(__fmul_rn(q, x2), 1.18534705686654e-04f);
  q = __fadd_rn(__fmul_rn(q, x2), 2.26843463243900e-03f);
  q = __fadd_rn(__fmul_rn(q, x2), 4.89352518554385e-03f);
  float r = __fdiv_rn(p, q);
  return (fabsf(x) < 0.0004f) ? x : r;
}

// Quarter-wave-per-row scores; lane j owns the XLA vector-lane-j chain
// (elements 16k+j, k ascending, unfused mul+add), shfl 8/4/2/1 tree.
// Bit-identical to R3-R7 (passed). Fuses nodemap + lookback-state init.
// NO cross-block fences: kernel boundary is the sync (R6/R8/R9 lesson).
__global__ __launch_bounds__(256) void k_scores(const float* __restrict__ x,
                                                const float* __restrict__ w){
#pragma clang fp contract(off)
  int tid = threadIdx.x;
  int gid = blockIdx.x*256 + tid;
  if (gid < NTOTAL) g_nodemap[gid] = -1;              // fused nm_init
  if (blockIdx.x == 0){ g_state[tid] = 0ull; g_state[256+tid] = 0ull; }

  int grp = tid >> 4, j = tid & 15;
  int row = blockIdx.x*16 + grp;
  const float* rx = x + (size_t)row*NC;

  float wv[8];
#pragma unroll
  for (int k = 0; k < 8; ++k) wv[k] = w[k*16 + j];

  float an = 0.f, ad = 0.f;
#pragma unroll
  for (int k = 0; k < 8; ++k) an = __fadd_rn(an, __fmul_rn(wv[k], wv[k]));
#pragma unroll
  for (int k = 0; k < 8; ++k) ad = __fadd_rn(ad, __fmul_rn(rx[k*16 + j], wv[k]));

  float o;
  o = __shfl_down(an, 8); if (j < 8) an = __fadd_rn(an, o);
  o = __shfl_down(ad, 8); if (j < 8) ad = __fadd_rn(ad, o);
  o = __shfl_down(an, 4); if (j < 4) an = __fadd_rn(an, o);
  o = __shfl_down(ad, 4); if (j < 4) ad = __fadd_rn(ad, o);
  o = __shfl_down(an, 2); if (j < 2) an = __fadd_rn(an, o);
  o = __shfl_down(ad, 2); if (j < 2) ad = __fadd_rn(ad, o);
  o = __shfl_down(an, 1);
  float o2 = __shfl_down(ad, 1);
  if (j == 0){
    float nrm = __fsqrt_rn(__fadd_rn(an, o));
    float acc = __fadd_rn(ad, o2);
    float t = __fdiv_rn(acc, nrm);
    g_scores[row] = xla_tanhf(t);
  }
}

// Sentence key: ascending u64 == (score descending, index ascending).
__device__ __forceinline__ unsigned long long skey(float s, int idx){
  uint32_t u = __float_as_uint(s);
  u = (u & 0x80000000u) ? ~u : (u | 0x80000000u);
  u = ~u;
  return ((unsigned long long)u << 32) | (uint32_t)idx;
}

// One block per graph: sentence top-3 via 3 block-min extractions; other
// top-1792 via stable LSD radix (4x8-bit). Sets nodemap + kept-bitmap words
// for its own graph (128 words, built in LDS). (R5/R7 verbatim, passed.)
__global__ __launch_bounds__(512) void k_topk(){
  __shared__ uint32_t keyA[NOTHER], keyB[NOTHER];
  __shared__ uint16_t idxA[NOTHER], idxB[NOTHER], rnk[NOTHER];
  __shared__ uint16_t cnt[8][256];
  __shared__ uint16_t tot[256], dbase[256];
  __shared__ unsigned long long smin[8];
  __shared__ unsigned long long swin;
  __shared__ uint32_t bl[NN/32];   // 128 words: this graph's kept bitmap

  int g = blockIdx.x, tid = threadIdx.x;
  int lane = tid & 63, wv = tid >> 6;
  const float* sg = g_scores + g*NN;

  if (tid < NN/32) bl[tid] = 0u;
  __syncthreads();

  unsigned long long key = skey(sg[tid], tid);
  for (int t = 0; t < KSENT; ++t){
    unsigned long long v = key;
#pragma unroll
    for (int off = 32; off; off >>= 1){
      unsigned long long o = __shfl_down(v, off);
      v = (o < v) ? o : v;
    }
    if (lane == 0) smin[wv] = v;
    __syncthreads();
    if (tid == 0){
      unsigned long long mm = smin[0];
      for (int w2 = 1; w2 < 8; ++w2) if (smin[w2] < mm) mm = smin[w2];
      swin = mm;
    }
    __syncthreads();
    unsigned long long winner = swin;
    if (key == winner){
      int idx = (int)(winner & 0xFFFFFFFFull);
      int node = g*NN + idx, p = g*KSENT + t;
      g_perm[p] = node;
      g_nodemap[node] = p;
      atomicOr(&bl[idx >> 5], 1u << (idx & 31));
      key = ~0ull;
    }
    __syncthreads();
  }

  for (int i = tid; i < NOTHER; i += 512){
    uint32_t u = __float_as_uint(sg[NS + i]);
    u = (u & 0x80000000u) ? ~u : (u | 0x80000000u);
    keyA[i] = ~u;
    idxA[i] = (uint16_t)i;
  }
  __syncthreads();

  uint32_t* ksrc = keyA; uint32_t* kdst = keyB;
  uint16_t* isrc = idxA; uint16_t* idst = idxB;
  unsigned long long ltmask = (1ull << lane) - 1ull;
  int base = wv * 448;

  for (int pass = 0; pass < 4; ++pass){
    int shift = pass * 8;
    uint32_t* c32 = (uint32_t*)cnt[wv];
    c32[lane] = 0; c32[64 + lane] = 0;
    for (int r = 0; r < 7; ++r){
      int i = base + r*64 + lane;
      uint32_t k = ksrc[i];
      uint32_t d = (k >> shift) & 255u;
      unsigned long long m = ~0ull;
#pragma unroll
      for (int b = 0; b < 8; ++b){
        unsigned long long bb = __ballot((d >> b) & 1u);
        m &= ((d >> b) & 1u) ? bb : ~bb;
      }
      int rir = __popcll(m & ltmask);
      uint16_t bse = cnt[wv][d];
      rnk[i] = (uint16_t)(bse + rir);
      if ((m >> lane) == 1ull)
        cnt[wv][d] = (uint16_t)(bse + __popcll(m));
    }
    __syncthreads();
    if (tid < 256){
      int s = 0;
#pragma unroll
      for (int w2 = 0; w2 < 8; ++w2){
        int t2 = cnt[w2][tid]; cnt[w2][tid] = (uint16_t)s; s += t2;
      }
      tot[tid] = (uint16_t)s;
    }
    __syncthreads();
    if (tid < 64){
      int b4 = tid*4;
      int s0=tot[b4], s1=tot[b4+1], s2=tot[b4+2], s3=tot[b4+3];
      int lsum = s0+s1+s2+s3;
      int sc = lsum;
      for (int off = 1; off < 64; off <<= 1){
        int vv = __shfl_up(sc, off);
        if (lane >= off) sc += vv;
      }
      int excl = sc - lsum;
      dbase[b4]   = (uint16_t)excl;
      dbase[b4+1] = (uint16_t)(excl + s0);
      dbase[b4+2] = (uint16_t)(excl + s0 + s1);
      dbase[b4+3] = (uint16_t)(excl + s0 + s1 + s2);
    }
    __syncthreads();
    {
      int idx = tid;
#pragma unroll
      for (int kk = 0; kk < 4; ++kk){
        int w2 = (idx >> 8) & 7, d2 = idx & 255;
        cnt[w2][d2] = (uint16_t)(cnt[w2][d2] + dbase[d2]);
        idx += 512;
      }
    }
    __syncthreads();
    for (int r = 0; r < 7; ++r){
      int i = base + r*64 + lane;
      uint32_t k = ksrc[i];
      uint32_t d = (k >> shift) & 255u;
      int dest = cnt[wv][d] + rnk[i];
      kdst[dest] = k; idst[dest] = isrc[i];
    }
    __syncthreads();
    uint32_t* tk = ksrc; ksrc = kdst; kdst = tk;
    uint16_t* ti = isrc; isrc = idst; idst = ti;
  }
  for (int j = tid; j < KOTHER; j += 512){
    int li = NS + (int)isrc[j];
    int node = g*NN + li;
    int p = NSENT_TOT + g*KOTHER + j;
    g_perm[p] = node;
    g_nodemap[node] = p;
    atomicOr(&bl[li >> 5], 1u << (li & 31));
  }
  __syncthreads();
  if (tid < NN/32) g_bits[g*(NN/32) + tid] = bl[tid];
}

// k2: blocks 0..511 = edges; blocks 512..1535 = gather.
// Edge phase v2: 16 consecutive edges/thread (thread-major order == original
// order => stable), uint4 loads, 16-bit keep mask, ONE block scan, direct
// dense writes (no stash, no overflow path). LDS 32.8 KB -> 4 blocks/CU.
__global__ __launch_bounds__(512) void k2(const int* __restrict__ ei,
                                          const float* __restrict__ x,
                                          float* __restrict__ out){
  __shared__ uint32_t bm[NBW];    // 32 KB
  __shared__ int wsum[8];
  __shared__ int s_off;
  int b = blockIdx.x, tid = threadIdx.x;

  if (b >= NEBLK){
    // ---------------- gather + side outputs (R7 verbatim) ----------------
    const size_t total4 = (size_t)NP*NC/4;
    for (size_t q = (size_t)(b - NEBLK)*512 + tid; q < total4;
         q += (size_t)NGB*512){
      int p  = (int)(q >> 5);
      int c4 = (int)(q & 31);
      int node = g_perm[p];
      float s = g_scores[node];
      float4 v = *(const float4*)(x + (size_t)node*NC + c4*4);
      float4 o;
      o.x = bfr(__fmul_rn(v.x, s));
      o.y = bfr(__fmul_rn(v.y, s));
      o.z = bfr(__fmul_rn(v.z, s));
      o.w = bfr(__fmul_rn(v.w, s));
      *(float4*)(out + OFF_X + (size_t)p*NC + c4*4) = o;
      if (c4 == 0){
        out[OFF_BATCH + p] = bfr((float)(node >> 12));
        out[OFF_PERM  + p] = bfr((float)node);
        out[OFF_SCORE + p] = bfr(s);
      }
    }
    return;
  }

  // ---------------- edges ----------------
  int lane = tid & 63, wid = tid >> 6;
  int base = b * EPB;
  int e0 = base + tid*16;         // this thread's 16 consecutive edges

  { // stage bitmap: 8192 words / 512 thr = 4 x dwordx4
    uint4* d4 = (uint4*)bm;
    const uint4* s4 = (const uint4*)g_bits;
#pragma unroll
    for (int kk = 0; kk < 4; ++kk) d4[tid + kk*512] = s4[tid + kk*512];
  }
  if (tid == 0) s_off = 0;
  __syncthreads();

  // Phase A: keep mask for 16 edges (vectorized loads, LDS bitmap test)
  uint32_t mask = 0;
  {
    const uint4* r0 = (const uint4*)(ei + e0);
    const uint4* r1 = (const uint4*)(ei + (size_t)NE + e0);
#pragma unroll
    for (int k = 0; k < 4; ++k){
      uint4 uu = r0[k], vv = r1[k];
      uint32_t b0 = (bm[uu.x>>5] >> (uu.x&31)) & (bm[vv.x>>5] >> (vv.x&31)) & 1u;
      uint32_t b1 = (bm[uu.y>>5] >> (uu.y&31)) & (bm[vv.y>>5] >> (vv.y&31)) & 1u;
      uint32_t b2 = (bm[uu.z>>5] >> (uu.z&31)) & (bm[vv.z>>5] >> (vv.z&31)) & 1u;
      uint32_t b3 = (bm[uu.w>>5] >> (uu.w&31)) & (bm[vv.w>>5] >> (vv.w&31)) & 1u;
      mask |= (b0 | (b1<<1) | (b2<<2) | (b3<<3)) << (k*4);
    }
  }
  int c = __popc(mask);

  // ONE block scan (thread order == edge order => stable positions)
  int sc = c;
  for (int off = 1; off < 64; off <<= 1){
    int v = __shfl_up(sc, off);
    if (lane >= off) sc += v;
  }
  if (lane == 63) wsum[wid] = sc;
  __syncthreads();
  int wbase = 0, myc = 0;
#pragma unroll
  for (int w2 = 0; w2 < 8; ++w2){
    int t2 = wsum[w2];
    if (w2 < wid) wbase += t2;
    myc += t2;
  }
  int myoff = wbase + sc - c;

  // Phase B: decoupled lookback (wave 0) — relaxed atomics only (R4-R9)
  if (b == 0){
    if (tid == 0)
      atomicExch(&g_state[0], FLG_INC | (unsigned long long)(uint32_t)myc);
  } else if (wid == 0){
    if (lane == 0)
      atomicExch(&g_state[b], FLG_AGG | (unsigned long long)(uint32_t)myc);
    int prev = 0, win = b - 1;
    bool done = false;
    while (!done){
      int idxl = win - lane;
      unsigned long long st = (idxl >= 0) ? atomicAdd(&g_state[idxl], 0ull)
                                          : FLG_INC;
      unsigned f = (unsigned)(st >> 62);
      unsigned long long readym = __ballot(f != 0u);
      unsigned long long incm   = __ballot(f == 2u);
      if (incm){
        int l0 = __ffsll((long long)incm) - 1;
        unsigned long long needm = (l0 == 63) ? ~0ull : ((1ull << (l0+1)) - 1ull);
        if ((readym & needm) == needm){
          int contrib = (lane <= l0) ? (int)(uint32_t)st : 0;
#pragma unroll
          for (int off = 32; off; off >>= 1)
            contrib += __shfl_down(contrib, off);
          if (lane == 0) prev += contrib;
          done = true;
        }
      } else if (readym == ~0ull){
        int contrib = (int)(uint32_t)st;
#pragma unroll
        for (int off = 32; off; off >>= 1)
          contrib += __shfl_down(contrib, off);
        if (lane == 0) prev += contrib;
        win -= 64;
      } else {
        __builtin_amdgcn_s_sleep(2);
      }
    }
    if (lane == 0){
      atomicExch(&g_state[b], FLG_INC | (unsigned long long)(uint32_t)(prev + myc));
      s_off = prev;
      if (b == NEBLK-1)
        out[OFF_NE] = bfr((float)(prev + myc));
    }
  }
  __syncthreads();
  int off = s_off;

  // Phase C: direct dense writes in original order (ei re-read is L2-hot)
  {
    int pos = off + myoff;
    uint32_t mm = mask;
    while (mm){
      int k = __ffs(mm) - 1; mm &= mm - 1;
      int e = e0 + k;
      int u = ei[e], v = ei[(size_t)NE + e];
      out[OFF_EDGE + pos]      = bfr((float)g_nodemap[u]);
      out[OFF_EDGE + NE + pos] = bfr((float)g_nodemap[v]);
      ++pos;
    }
  }

  // Tail drop-slice: block b fills [NE - dropoff - drops, NE - dropoff)
  // with -1 in both rows. Slices tile [T, NE) exactly; values identical.
  int drops = EPB - myc;
  int dropoff = base - off;
  int t0 = NE - dropoff - drops;
  for (int i = tid; i < drops; i += 512){
    out[OFF_EDGE + t0 + i]      = -1.0f;
    out[OFF_EDGE + NE + t0 + i] = -1.0f;
  }
}

extern "C" void kernel_launch(void* const* d_in, const int* in_sizes, int n_in,
                              void* d_out, int out_size, void* d_ws, size_t ws_size,
                              hipStream_t stream) {
  const float* x = (const float*)d_in[0];
  const float* w = (const float*)d_in[1];
  const int*   ei = (const int*)d_in[2];
  float* out = (float*)d_out;

  hipLaunchKernelGGL(k_scores, dim3(NTOTAL/16),   dim3(256), 0, stream, x, w);
  hipLaunchKernelGGL(k_topk,   dim3(NB),          dim3(512), 0, stream);
  hipLaunchKernelGGL(k2,       dim3(NEBLK + NGB), dim3(512), 0, stream, ei, x, out);
}

// Round 11
// 93.602 us; speedup vs baseline: 2.3623x; 1.1187x over previous
//
#include <hip/hip_runtime.h>
#include <hip/hip_bf16.h>
#include <stdint.h>

// Problem constants (static graph layout)
#define NB 64
#define NN 4096
#define NS 512
#define NC 128
#define NTOTAL (NB*NN)          // 262144
#define NE 4194304
#define KSENT 3
#define KOTHER 1792
#define KPG (KSENT+KOTHER)      // 1795
#define NP (NB*KPG)             // 114880
#define NSENT_TOT (NB*KSENT)    // 192
#define NOTHER (NN-NS)          // 3584

// d_out element offsets (f32 elements), concatenated flat in return order:
// x_out[114880,128], edge_index_new[2,E], batch_out[P], perm[P], score[P], num_edges[1]
#define OFF_X     0ull
#define OFF_EDGE  14704640ull
#define OFF_BATCH 23093248ull
#define OFF_PERM  23208128ull
#define OFF_SCORE 23323008ull
#define OFF_NE    23437888ull

#define NEBLK 512               // edge blocks
#define EPB   (NE/NEBLK)        // 8192 edges per block (16 chunks of 512)
#define STASH 2560              // kept/block: mean 1575, sd 36 -> +27 sigma
#define NGB   1024              // gather blocks
#define NBW   (NTOTAL/32)       // 8192 bitmap words

#define FLG_AGG (1ull<<62)
#define FLG_INC (2ull<<62)

// Module-scope scratch. ~2.5 MB.
__device__ float g_scores[NTOTAL];
__device__ int   g_perm[NP];
__device__ int   g_nodemap[NTOTAL];
__device__ uint32_t g_bits[NBW];               // kept-node bitmap
__device__ unsigned long long g_state[NEBLK];  // lookback: flag(2b)|value(32b)

// f32 -> bf16 RNE, kept as f32. Ref is bf16-rounded.
__device__ __forceinline__ float bfr(float f){
  uint32_t u = __float_as_uint(f);
  uint32_t r = u + 0x7FFFu + ((u >> 16) & 1u);
  return __uint_as_float(r & 0xFFFF0000u);
}

// Bit-exact XLA:CPU EmitTanh (f32). Passing R2-R10.
__device__ __forceinline__ float xla_tanhf(float x){
#pragma clang fp contract(off)
  float xc = fminf(fmaxf(x, -7.90531110763549805f), 7.90531110763549805f);
  float x2 = __fmul_rn(xc, xc);
  float p = -2.76076847742355e-16f;
  p = __fadd_rn(__fmul_rn(p, x2),  2.00018790482477e-13f);
  p = __fadd_rn(__fmul_rn(p, x2), -8.60467152213735e-11f);
  p = __fadd_rn(__fmul_rn(p, x2),  5.12229709037114e-08f);
  p = __fadd_rn(__fmul_rn(p, x2),  1.48572235717979e-05f);
  p = __fadd_rn(__fmul_rn(p, x2),  6.37261928875436e-04f);
  p = __fadd_rn(__fmul_rn(p, x2),  4.89352455891786e-03f);
  p = __fmul_rn(xc, p);
  float q = 1.19825839466702e-06f;
  q = __fadd_rn(__fmul_rn(q, x2), 1.18534705686654e-04f);
  q = __fadd_rn(__fmul_rn(q, x2), 2.26843463243900e-03f);
  q = __fadd_rn(__fmul_rn(q, x2), 4.89352518554385e-03f);
  float r = __fdiv_rn(p, q);
  return (fabsf(x) < 0.0004f) ? x : r;
}

// Quarter-wave-per-row scores; lane j owns the XLA vector-lane-j chain
// (elements 16k+j, k ascending, unfused mul+add), shfl 8/4/2/1 tree.
// Bit-identical to R3-R10 (passed). Fuses nodemap + lookback-state init.
// NO cross-block fences: kernel boundary is the sync (R6/R8/R9 lesson).
__global__ __launch_bounds__(256) void k_scores(const float* __restrict__ x,
                                                const float* __restrict__ w){
#pragma clang fp contract(off)
  int tid = threadIdx.x;
  int gid = blockIdx.x*256 + tid;
  if (gid < NTOTAL) g_nodemap[gid] = -1;              // fused nm_init
  if (blockIdx.x == 0){ g_state[tid] = 0ull; g_state[256+tid] = 0ull; }

  int grp = tid >> 4, j = tid & 15;
  int row = blockIdx.x*16 + grp;
  const float* rx = x + (size_t)row*NC;

  float wv[8];
#pragma unroll
  for (int k = 0; k < 8; ++k) wv[k] = w[k*16 + j];

  float an = 0.f, ad = 0.f;
#pragma unroll
  for (int k = 0; k < 8; ++k) an = __fadd_rn(an, __fmul_rn(wv[k], wv[k]));
#pragma unroll
  for (int k = 0; k < 8; ++k) ad = __fadd_rn(ad, __fmul_rn(rx[k*16 + j], wv[k]));

  float o;
  o = __shfl_down(an, 8); if (j < 8) an = __fadd_rn(an, o);
  o = __shfl_down(ad, 8); if (j < 8) ad = __fadd_rn(ad, o);
  o = __shfl_down(an, 4); if (j < 4) an = __fadd_rn(an, o);
  o = __shfl_down(ad, 4); if (j < 4) ad = __fadd_rn(ad, o);
  o = __shfl_down(an, 2); if (j < 2) an = __fadd_rn(an, o);
  o = __shfl_down(ad, 2); if (j < 2) ad = __fadd_rn(ad, o);
  o = __shfl_down(an, 1);
  float o2 = __shfl_down(ad, 1);
  if (j == 0){
    float nrm = __fsqrt_rn(__fadd_rn(an, o));
    float acc = __fadd_rn(ad, o2);
    float t = __fdiv_rn(acc, nrm);
    g_scores[row] = xla_tanhf(t);
  }
}

// Sentence key: ascending u64 == (score descending, index ascending).
__device__ __forceinline__ unsigned long long skey(float s, int idx){
  uint32_t u = __float_as_uint(s);
  u = (u & 0x80000000u) ? ~u : (u | 0x80000000u);
  u = ~u;
  return ((unsigned long long)u << 32) | (uint32_t)idx;
}

// One block per graph: sentence top-3 via 3 block-min extractions; other
// top-1792 via stable LSD radix (4x8-bit). Sets nodemap + kept-bitmap words
// for its own graph (128 words, built in LDS). (R5/R7 verbatim, passed.)
__global__ __launch_bounds__(512) void k_topk(){
  __shared__ uint32_t keyA[NOTHER], keyB[NOTHER];
  __shared__ uint16_t idxA[NOTHER], idxB[NOTHER], rnk[NOTHER];
  __shared__ uint16_t cnt[8][256];
  __shared__ uint16_t tot[256], dbase[256];
  __shared__ unsigned long long smin[8];
  __shared__ unsigned long long swin;
  __shared__ uint32_t bl[NN/32];   // 128 words: this graph's kept bitmap

  int g = blockIdx.x, tid = threadIdx.x;
  int lane = tid & 63, wv = tid >> 6;
  const float* sg = g_scores + g*NN;

  if (tid < NN/32) bl[tid] = 0u;
  __syncthreads();

  unsigned long long key = skey(sg[tid], tid);
  for (int t = 0; t < KSENT; ++t){
    unsigned long long v = key;
#pragma unroll
    for (int off = 32; off; off >>= 1){
      unsigned long long o = __shfl_down(v, off);
      v = (o < v) ? o : v;
    }
    if (lane == 0) smin[wv] = v;
    __syncthreads();
    if (tid == 0){
      unsigned long long mm = smin[0];
      for (int w2 = 1; w2 < 8; ++w2) if (smin[w2] < mm) mm = smin[w2];
      swin = mm;
    }
    __syncthreads();
    unsigned long long winner = swin;
    if (key == winner){
      int idx = (int)(winner & 0xFFFFFFFFull);
      int node = g*NN + idx, p = g*KSENT + t;
      g_perm[p] = node;
      g_nodemap[node] = p;
      atomicOr(&bl[idx >> 5], 1u << (idx & 31));
      key = ~0ull;
    }
    __syncthreads();
  }

  for (int i = tid; i < NOTHER; i += 512){
    uint32_t u = __float_as_uint(sg[NS + i]);
    u = (u & 0x80000000u) ? ~u : (u | 0x80000000u);
    keyA[i] = ~u;
    idxA[i] = (uint16_t)i;
  }
  __syncthreads();

  uint32_t* ksrc = keyA; uint32_t* kdst = keyB;
  uint16_t* isrc = idxA; uint16_t* idst = idxB;
  unsigned long long ltmask = (1ull << lane) - 1ull;
  int base = wv * 448;

  for (int pass = 0; pass < 4; ++pass){
    int shift = pass * 8;
    uint32_t* c32 = (uint32_t*)cnt[wv];
    c32[lane] = 0; c32[64 + lane] = 0;
    for (int r = 0; r < 7; ++r){
      int i = base + r*64 + lane;
      uint32_t k = ksrc[i];
      uint32_t d = (k >> shift) & 255u;
      unsigned long long m = ~0ull;
#pragma unroll
      for (int b = 0; b < 8; ++b){
        unsigned long long bb = __ballot((d >> b) & 1u);
        m &= ((d >> b) & 1u) ? bb : ~bb;
      }
      int rir = __popcll(m & ltmask);
      uint16_t bse = cnt[wv][d];
      rnk[i] = (uint16_t)(bse + rir);
      if ((m >> lane) == 1ull)
        cnt[wv][d] = (uint16_t)(bse + __popcll(m));
    }
    __syncthreads();
    if (tid < 256){
      int s = 0;
#pragma unroll
      for (int w2 = 0; w2 < 8; ++w2){
        int t2 = cnt[w2][tid]; cnt[w2][tid] = (uint16_t)s; s += t2;
      }
      tot[tid] = (uint16_t)s;
    }
    __syncthreads();
    if (tid < 64){
      int b4 = tid*4;
      int s0=tot[b4], s1=tot[b4+1], s2=tot[b4+2], s3=tot[b4+3];
      int lsum = s0+s1+s2+s3;
      int sc = lsum;
      for (int off = 1; off < 64; off <<= 1){
        int vv = __shfl_up(sc, off);
        if (lane >= off) sc += vv;
      }
      int excl = sc - lsum;
      dbase[b4]   = (uint16_t)excl;
      dbase[b4+1] = (uint16_t)(excl + s0);
      dbase[b4+2] = (uint16_t)(excl + s0 + s1);
      dbase[b4+3] = (uint16_t)(excl + s0 + s1 + s2);
    }
    __syncthreads();
    {
      int idx = tid;
#pragma unroll
      for (int kk = 0; kk < 4; ++kk){
        int w2 = (idx >> 8) & 7, d2 = idx & 255;
        cnt[w2][d2] = (uint16_t)(cnt[w2][d2] + dbase[d2]);
        idx += 512;
      }
    }
    __syncthreads();
    for (int r = 0; r < 7; ++r){
      int i = base + r*64 + lane;
      uint32_t k = ksrc[i];
      uint32_t d = (k >> shift) & 255u;
      int dest = cnt[wv][d] + rnk[i];
      kdst[dest] = k; idst[dest] = isrc[i];
    }
    __syncthreads();
    uint32_t* tk = ksrc; ksrc = kdst; kdst = tk;
    uint16_t* ti = isrc; isrc = idst; idst = ti;
  }
  for (int j = tid; j < KOTHER; j += 512){
    int li = NS + (int)isrc[j];
    int node = g*NN + li;
    int p = NSENT_TOT + g*KOTHER + j;
    g_perm[p] = node;
    g_nodemap[node] = p;
    atomicOr(&bl[li >> 5], 1u << (li & 31));
  }
  __syncthreads();
  if (tid < NN/32) g_bits[g*(NN/32) + tid] = bl[tid];
}

// k2: blocks 0..511 = edges; blocks 512..1535 = gather.
// Edge phase v3: R7's memory patterns (strided coalesced chunk loads, LDS
// stash, dense coalesced writes) but 34 barriers -> 3: per-chunk ballots fill
// a 128-entry (chunk,wave) count table; ONE barrier; positions derived from
// broadcast-read table + packed lane prefixes. Positions == R7's (chunk-major
// == original edge order => stable, identical output).
__global__ __launch_bounds__(512) void k2(const int* __restrict__ ei,
                                          const float* __restrict__ x,
                                          float* __restrict__ out){
  __shared__ uint32_t bm[NBW];    // 32 KB
  __shared__ int2 rc[STASH];      // 20 KB
  __shared__ int wcnt[128];       // [chunk s][wave w] kept counts
  __shared__ int s_off;
  int b = blockIdx.x, tid = threadIdx.x;

  if (b >= NEBLK){
    // ---------------- gather + side outputs (R7 verbatim) ----------------
    const size_t total4 = (size_t)NP*NC/4;
    for (size_t q = (size_t)(b - NEBLK)*512 + tid; q < total4;
         q += (size_t)NGB*512){
      int p  = (int)(q >> 5);
      int c4 = (int)(q & 31);
      int node = g_perm[p];
      float s = g_scores[node];
      float4 v = *(const float4*)(x + (size_t)node*NC + c4*4);
      float4 o;
      o.x = bfr(__fmul_rn(v.x, s));
      o.y = bfr(__fmul_rn(v.y, s));
      o.z = bfr(__fmul_rn(v.z, s));
      o.w = bfr(__fmul_rn(v.w, s));
      *(float4*)(out + OFF_X + (size_t)p*NC + c4*4) = o;
      if (c4 == 0){
        out[OFF_BATCH + p] = bfr((float)(node >> 12));
        out[OFF_PERM  + p] = bfr((float)node);
        out[OFF_SCORE + p] = bfr(s);
      }
    }
    return;
  }

  // ---------------- edges ----------------
  int lane = tid & 63, wid = tid >> 6;
  int base = b * EPB;
  unsigned long long ltm = (1ull << lane) - 1ull;

  { // stage bitmap: 8192 words / 512 thr = 4 x dwordx4
    uint4* d4 = (uint4*)bm;
    const uint4* s4 = (const uint4*)g_bits;
#pragma unroll
    for (int kk = 0; kk < 4; ++kk) d4[tid + kk*512] = s4[tid + kk*512];
  }
  if (tid == 0) s_off = 0;
  __syncthreads();   // [barrier 1] bitmap ready

  // Phase A: 16 strided chunks (coalesced, same pattern as R7), no barriers
  uint32_t keep16 = 0;
#pragma unroll
  for (int s = 0; s < 16; ++s){
    int e = base + s*512 + tid;
    uint32_t u = (uint32_t)ei[e], v = (uint32_t)ei[(size_t)NE + e];
    keep16 |= (((bm[u>>5] >> (u&31)) & (bm[v>>5] >> (v&31)) & 1u) << s);
  }
  uint32_t lpack[4] = {0,0,0,0};   // per-chunk lane prefix, 8-bit fields
#pragma unroll
  for (int s = 0; s < 16; ++s){
    unsigned long long m = __ballot((keep16 >> s) & 1u);
    lpack[s>>2] |= ((uint32_t)__popcll(m & ltm)) << ((s&3)*8);
    if (lane == 0) wcnt[s*8 + wid] = __popcll(m);
  }
  __syncthreads();   // [barrier 2] count table ready

  // Stash kept (r,c) at stable positions (chunk-major => original order).
  // Table reads are wave-uniform => LDS broadcast, no conflicts.
  int run = 0;
#pragma unroll
  for (int s = 0; s < 16; ++s){
    int wb = 0, tot = 0;
#pragma unroll
    for (int w2 = 0; w2 < 8; ++w2){
      int t2 = wcnt[s*8 + w2];
      wb += (w2 < wid) ? t2 : 0;
      tot += t2;
    }
    if ((keep16 >> s) & 1u){
      int lp = (int)((lpack[s>>2] >> ((s&3)*8)) & 255u);
      int posL = run + wb + lp;
      if (posL < STASH){
        int e = base + s*512 + tid;       // L1/L2-hot re-read
        int2 p;
        p.x = g_nodemap[ei[e]];
        p.y = g_nodemap[ei[(size_t)NE + e]];
        rc[posL] = p;
      }
    }
    run += tot;
  }
  int myc = run;

  // Phase B: decoupled lookback (wave 0) — relaxed atomics only (R4-R10)
  if (b == 0){
    if (tid == 0)
      atomicExch(&g_state[0], FLG_INC | (unsigned long long)(uint32_t)myc);
  } else if (wid == 0){
    if (lane == 0)
      atomicExch(&g_state[b], FLG_AGG | (unsigned long long)(uint32_t)myc);
    int prev = 0, win = b - 1;
    bool done = false;
    while (!done){
      int idxl = win - lane;
      unsigned long long st = (idxl >= 0) ? atomicAdd(&g_state[idxl], 0ull)
                                          : FLG_INC;
      unsigned f = (unsigned)(st >> 62);
      unsigned long long readym = __ballot(f != 0u);
      unsigned long long incm   = __ballot(f == 2u);
      if (incm){
        int l0 = __ffsll((long long)incm) - 1;
        unsigned long long needm = (l0 == 63) ? ~0ull : ((1ull << (l0+1)) - 1ull);
        if ((readym & needm) == needm){
          int contrib = (lane <= l0) ? (int)(uint32_t)st : 0;
#pragma unroll
          for (int off = 32; off; off >>= 1)
            contrib += __shfl_down(contrib, off);
          if (lane == 0) prev += contrib;
          done = true;
        }
      } else if (readym == ~0ull){
        int contrib = (int)(uint32_t)st;
#pragma unroll
        for (int off = 32; off; off >>= 1)
          contrib += __shfl_down(contrib, off);
        if (lane == 0) prev += contrib;
        win -= 64;
      } else {
        __builtin_amdgcn_s_sleep(2);
      }
    }
    if (lane == 0){
      atomicExch(&g_state[b], FLG_INC | (unsigned long long)(uint32_t)(prev + myc));
      s_off = prev;
      if (b == NEBLK-1)
        out[OFF_NE] = bfr((float)(prev + myc));
    }
  }
  __syncthreads();   // [barrier 3] stash + s_off ready
  int off = s_off;

  // Phase C: coalesced dense writes from stash (R7 verbatim)
  int lim = myc < STASH ? myc : STASH;
  for (int i = tid; i < lim; i += 512){
    int2 p = rc[i];
    out[OFF_EDGE + off + i]      = bfr((float)p.x);
    out[OFF_EDGE + NE + off + i] = bfr((float)p.y);
  }
  // Overflow fallback (+27 sigma, ~never): direct writes for posL >= STASH
  if (myc > STASH){
    int run2 = 0;
#pragma unroll
    for (int s = 0; s < 16; ++s){
      int wb = 0, tot = 0;
#pragma unroll
      for (int w2 = 0; w2 < 8; ++w2){
        int t2 = wcnt[s*8 + w2];
        wb += (w2 < wid) ? t2 : 0;
        tot += t2;
      }
      if ((keep16 >> s) & 1u){
        int lp = (int)((lpack[s>>2] >> ((s&3)*8)) & 255u);
        int posL = run2 + wb + lp;
        if (posL >= STASH){
          int e = base + s*512 + tid;
          out[OFF_EDGE + off + posL]      = bfr((float)g_nodemap[ei[e]]);
          out[OFF_EDGE + NE + off + posL] = bfr((float)g_nodemap[ei[(size_t)NE + e]]);
        }
      }
      run2 += tot;
    }
  }

  // Tail drop-slice fill, float4-vectorized: block b owns
  // [NE - dropoff - drops, NE - dropoff) in both rows (tiles [T,NE) exactly).
  int drops = EPB - myc;
  int dropoff = base - off;
  size_t t0 = (size_t)(NE - dropoff - drops);
  float4 mv4; mv4.x = mv4.y = mv4.z = mv4.w = -1.0f;
#pragma unroll
  for (int r2 = 0; r2 < 2; ++r2){
    size_t st = OFF_EDGE + (size_t)r2*NE + t0;
    int head = (int)((4 - (st & 3)) & 3);
    if (head > drops) head = drops;
    for (int i = tid; i < head; i += 512) out[st + i] = -1.0f;
    int nv = (drops - head) >> 2;
    float4* p4 = (float4*)(out + st + head);
    for (int i = tid; i < nv; i += 512) p4[i] = mv4;
    int rem = drops - head - (nv << 2);
    size_t rbase = st + head + ((size_t)nv << 2);
    for (int i = tid; i < rem; i += 512) out[rbase + i] = -1.0f;
  }
}

extern "C" void kernel_launch(void* const* d_in, const int* in_sizes, int n_in,
                              void* d_out, int out_size, void* d_ws, size_t ws_size,
                              hipStream_t stream) {
  const float* x = (const float*)d_in[0];
  const float* w = (const float*)d_in[1];
  const int*   ei = (const int*)d_in[2];
  float* out = (float*)d_out;

  hipLaunchKernelGGL(k_scores, dim3(NTOTAL/16),   dim3(256), 0, stream, x, w);
  hipLaunchKernelGGL(k_topk,   dim3(NB),          dim3(512), 0, stream);
  hipLaunchKernelGGL(k2,       dim3(NEBLK + NGB), dim3(512), 0, stream, ei, x, out);
}

// Round 12
// 91.063 us; speedup vs baseline: 2.4281x; 1.0279x over previous
//
#include <hip/hip_runtime.h>
#include <hip/hip_bf16.h>
#include <stdint.h>

// Problem constants (static graph layout)
#define NB 64
#define NN 4096
#define NS 512
#define NC 128
#define NTOTAL (NB*NN)          // 262144
#define NE 4194304
#define KSENT 3
#define KOTHER 1792
#define KPG (KSENT+KOTHER)      // 1795
#define NP (NB*KPG)             // 114880
#define NSENT_TOT (NB*KSENT)    // 192
#define NOTHER (NN-NS)          // 3584

// d_out element offsets (f32 elements), concatenated flat in return order:
// x_out[114880,128], edge_index_new[2,E], batch_out[P], perm[P], score[P], num_edges[1]
#define OFF_X     0ull
#define OFF_EDGE  14704640ull
#define OFF_BATCH 23093248ull
#define OFF_PERM  23208128ull
#define OFF_SCORE 23323008ull
#define OFF_NE    23437888ull

#define NEBLK 512               // edge blocks
#define EPB   (NE/NEBLK)        // 8192 edges per block
#define STASH 2560              // kept/block: mean 1575, sd 36 -> +27 sigma
#define NGB   1024              // gather blocks
#define NBW   (NTOTAL/32)       // 8192 bitmap words

#define FLG_AGG (1ull<<62)
#define FLG_INC (2ull<<62)

// Module-scope scratch. ~2.5 MB.
__device__ float g_scores[NTOTAL];
__device__ int   g_perm[NP];
__device__ int   g_nodemap[NTOTAL];
__device__ uint32_t g_bits[NBW];               // kept-node bitmap
__device__ unsigned long long g_state[NEBLK];  // lookback: flag(2b)|value(32b)

// f32 -> bf16 RNE, kept as f32. Ref is bf16-rounded.
__device__ __forceinline__ float bfr(float f){
  uint32_t u = __float_as_uint(f);
  uint32_t r = u + 0x7FFFu + ((u >> 16) & 1u);
  return __uint_as_float(r & 0xFFFF0000u);
}

// Bit-exact XLA:CPU EmitTanh (f32). Passing R2-R11.
__device__ __forceinline__ float xla_tanhf(float x){
#pragma clang fp contract(off)
  float xc = fminf(fmaxf(x, -7.90531110763549805f), 7.90531110763549805f);
  float x2 = __fmul_rn(xc, xc);
  float p = -2.76076847742355e-16f;
  p = __fadd_rn(__fmul_rn(p, x2),  2.00018790482477e-13f);
  p = __fadd_rn(__fmul_rn(p, x2), -8.60467152213735e-11f);
  p = __fadd_rn(__fmul_rn(p, x2),  5.12229709037114e-08f);
  p = __fadd_rn(__fmul_rn(p, x2),  1.48572235717979e-05f);
  p = __fadd_rn(__fmul_rn(p, x2),  6.37261928875436e-04f);
  p = __fadd_rn(__fmul_rn(p, x2),  4.89352455891786e-03f);
  p = __fmul_rn(xc, p);
  float q = 1.19825839466702e-06f;
  q = __fadd_rn(__fmul_rn(q, x2), 1.18534705686654e-04f);
  q = __fadd_rn(__fmul_rn(q, x2), 2.26843463243900e-03f);
  q = __fadd_rn(__fmul_rn(q, x2), 4.89352518554385e-03f);
  float r = __fdiv_rn(p, q);
  return (fabsf(x) < 0.0004f) ? x : r;
}

// Quarter-wave-per-row scores; lane j owns the XLA vector-lane-j chain
// (elements 16k+j, k ascending, unfused mul+add), shfl 8/4/2/1 tree.
// Bit-identical to R3-R11 (passed). Fuses nodemap + lookback-state init.
// NO cross-block fences: kernel boundary is the sync (R6/R8/R9 lesson).
__global__ __launch_bounds__(256) void k_scores(const float* __restrict__ x,
                                                const float* __restrict__ w){
#pragma clang fp contract(off)
  int tid = threadIdx.x;
  int gid = blockIdx.x*256 + tid;
  if (gid < NTOTAL) g_nodemap[gid] = -1;              // fused nm_init
  if (blockIdx.x == 0){ g_state[tid] = 0ull; g_state[256+tid] = 0ull; }

  int grp = tid >> 4, j = tid & 15;
  int row = blockIdx.x*16 + grp;
  const float* rx = x + (size_t)row*NC;

  float wv[8];
#pragma unroll
  for (int k = 0; k < 8; ++k) wv[k] = w[k*16 + j];

  float an = 0.f, ad = 0.f;
#pragma unroll
  for (int k = 0; k < 8; ++k) an = __fadd_rn(an, __fmul_rn(wv[k], wv[k]));
#pragma unroll
  for (int k = 0; k < 8; ++k) ad = __fadd_rn(ad, __fmul_rn(rx[k*16 + j], wv[k]));

  float o;
  o = __shfl_down(an, 8); if (j < 8) an = __fadd_rn(an, o);
  o = __shfl_down(ad, 8); if (j < 8) ad = __fadd_rn(ad, o);
  o = __shfl_down(an, 4); if (j < 4) an = __fadd_rn(an, o);
  o = __shfl_down(ad, 4); if (j < 4) ad = __fadd_rn(ad, o);
  o = __shfl_down(an, 2); if (j < 2) an = __fadd_rn(an, o);
  o = __shfl_down(ad, 2); if (j < 2) ad = __fadd_rn(ad, o);
  o = __shfl_down(an, 1);
  float o2 = __shfl_down(ad, 1);
  if (j == 0){
    float nrm = __fsqrt_rn(__fadd_rn(an, o));
    float acc = __fadd_rn(ad, o2);
    float t = __fdiv_rn(acc, nrm);
    g_scores[row] = xla_tanhf(t);
  }
}

// Sentence key: ascending u64 == (score descending, index ascending).
__device__ __forceinline__ unsigned long long skey(float s, int idx){
  uint32_t u = __float_as_uint(s);
  u = (u & 0x80000000u) ? ~u : (u | 0x80000000u);
  u = ~u;
  return ((unsigned long long)u << 32) | (uint32_t)idx;
}

// One block per graph: sentence top-3 via 3 block-min extractions; other
// top-1792 via stable LSD radix (4x8-bit). Sets nodemap + kept-bitmap words
// for its own graph (128 words, built in LDS). (R5/R7 verbatim, passed.)
__global__ __launch_bounds__(512) void k_topk(){
  __shared__ uint32_t keyA[NOTHER], keyB[NOTHER];
  __shared__ uint16_t idxA[NOTHER], idxB[NOTHER], rnk[NOTHER];
  __shared__ uint16_t cnt[8][256];
  __shared__ uint16_t tot[256], dbase[256];
  __shared__ unsigned long long smin[8];
  __shared__ unsigned long long swin;
  __shared__ uint32_t bl[NN/32];   // 128 words: this graph's kept bitmap

  int g = blockIdx.x, tid = threadIdx.x;
  int lane = tid & 63, wv = tid >> 6;
  const float* sg = g_scores + g*NN;

  if (tid < NN/32) bl[tid] = 0u;
  __syncthreads();

  unsigned long long key = skey(sg[tid], tid);
  for (int t = 0; t < KSENT; ++t){
    unsigned long long v = key;
#pragma unroll
    for (int off = 32; off; off >>= 1){
      unsigned long long o = __shfl_down(v, off);
      v = (o < v) ? o : v;
    }
    if (lane == 0) smin[wv] = v;
    __syncthreads();
    if (tid == 0){
      unsigned long long mm = smin[0];
      for (int w2 = 1; w2 < 8; ++w2) if (smin[w2] < mm) mm = smin[w2];
      swin = mm;
    }
    __syncthreads();
    unsigned long long winner = swin;
    if (key == winner){
      int idx = (int)(winner & 0xFFFFFFFFull);
      int node = g*NN + idx, p = g*KSENT + t;
      g_perm[p] = node;
      g_nodemap[node] = p;
      atomicOr(&bl[idx >> 5], 1u << (idx & 31));
      key = ~0ull;
    }
    __syncthreads();
  }

  for (int i = tid; i < NOTHER; i += 512){
    uint32_t u = __float_as_uint(sg[NS + i]);
    u = (u & 0x80000000u) ? ~u : (u | 0x80000000u);
    keyA[i] = ~u;
    idxA[i] = (uint16_t)i;
  }
  __syncthreads();

  uint32_t* ksrc = keyA; uint32_t* kdst = keyB;
  uint16_t* isrc = idxA; uint16_t* idst = idxB;
  unsigned long long ltmask = (1ull << lane) - 1ull;
  int base = wv * 448;

  for (int pass = 0; pass < 4; ++pass){
    int shift = pass * 8;
    uint32_t* c32 = (uint32_t*)cnt[wv];
    c32[lane] = 0; c32[64 + lane] = 0;
    for (int r = 0; r < 7; ++r){
      int i = base + r*64 + lane;
      uint32_t k = ksrc[i];
      uint32_t d = (k >> shift) & 255u;
      unsigned long long m = ~0ull;
#pragma unroll
      for (int b = 0; b < 8; ++b){
        unsigned long long bb = __ballot((d >> b) & 1u);
        m &= ((d >> b) & 1u) ? bb : ~bb;
      }
      int rir = __popcll(m & ltmask);
      uint16_t bse = cnt[wv][d];
      rnk[i] = (uint16_t)(bse + rir);
      if ((m >> lane) == 1ull)
        cnt[wv][d] = (uint16_t)(bse + __popcll(m));
    }
    __syncthreads();
    if (tid < 256){
      int s = 0;
#pragma unroll
      for (int w2 = 0; w2 < 8; ++w2){
        int t2 = cnt[w2][tid]; cnt[w2][tid] = (uint16_t)s; s += t2;
      }
      tot[tid] = (uint16_t)s;
    }
    __syncthreads();
    if (tid < 64){
      int b4 = tid*4;
      int s0=tot[b4], s1=tot[b4+1], s2=tot[b4+2], s3=tot[b4+3];
      int lsum = s0+s1+s2+s3;
      int sc = lsum;
      for (int off = 1; off < 64; off <<= 1){
        int vv = __shfl_up(sc, off);
        if (lane >= off) sc += vv;
      }
      int excl = sc - lsum;
      dbase[b4]   = (uint16_t)excl;
      dbase[b4+1] = (uint16_t)(excl + s0);
      dbase[b4+2] = (uint16_t)(excl + s0 + s1);
      dbase[b4+3] = (uint16_t)(excl + s0 + s1 + s2);
    }
    __syncthreads();
    {
      int idx = tid;
#pragma unroll
      for (int kk = 0; kk < 4; ++kk){
        int w2 = (idx >> 8) & 7, d2 = idx & 255;
        cnt[w2][d2] = (uint16_t)(cnt[w2][d2] + dbase[d2]);
        idx += 512;
      }
    }
    __syncthreads();
    for (int r = 0; r < 7; ++r){
      int i = base + r*64 + lane;
      uint32_t k = ksrc[i];
      uint32_t d = (k >> shift) & 255u;
      int dest = cnt[wv][d] + rnk[i];
      kdst[dest] = k; idst[dest] = isrc[i];
    }
    __syncthreads();
    uint32_t* tk = ksrc; ksrc = kdst; kdst = tk;
    uint16_t* ti = isrc; isrc = idst; idst = ti;
  }
  for (int j = tid; j < KOTHER; j += 512){
    int li = NS + (int)isrc[j];
    int node = g*NN + li;
    int p = NSENT_TOT + g*KOTHER + j;
    g_perm[p] = node;
    g_nodemap[node] = p;
    atomicOr(&bl[li >> 5], 1u << (li & 31));
  }
  __syncthreads();
  if (tid < NN/32) g_bits[g*(NN/32) + tid] = bl[tid];
}

// k2: blocks 0..511 = edges (bitmap keep-test, lookback compaction,
//     per-block tail drop-slice fill); blocks 512..1535 = gather.
// (R7 verbatim, passed at 90.9 us — best measured configuration.)
__global__ __launch_bounds__(512) void k2(const int* __restrict__ ei,
                                          const float* __restrict__ x,
                                          float* __restrict__ out){
  __shared__ uint32_t bm[NBW];    // 32 KB
  __shared__ int2 rc[STASH];      // 20 KB
  __shared__ int wsum[8];
  __shared__ int s_off;
  int b = blockIdx.x, tid = threadIdx.x;

  if (b >= NEBLK){
    // ---------------- gather + side outputs ----------------
    const size_t total4 = (size_t)NP*NC/4;
    for (size_t q = (size_t)(b - NEBLK)*512 + tid; q < total4;
         q += (size_t)NGB*512){
      int p  = (int)(q >> 5);
      int c4 = (int)(q & 31);
      int node = g_perm[p];
      float s = g_scores[node];
      float4 v = *(const float4*)(x + (size_t)node*NC + c4*4);
      float4 o;
      o.x = bfr(__fmul_rn(v.x, s));
      o.y = bfr(__fmul_rn(v.y, s));
      o.z = bfr(__fmul_rn(v.z, s));
      o.w = bfr(__fmul_rn(v.w, s));
      *(float4*)(out + OFF_X + (size_t)p*NC + c4*4) = o;
      if (c4 == 0){
        out[OFF_BATCH + p] = bfr((float)(node >> 12));
        out[OFF_PERM  + p] = bfr((float)node);
        out[OFF_SCORE + p] = bfr(s);
      }
    }
    return;
  }

  // ---------------- edges ----------------
  int lane = tid & 63, wid = tid >> 6;
  int base = b * EPB;
  unsigned long long ltm = (1ull << lane) - 1ull;

  { // stage bitmap: 8192 words / 512 thr = 4 x dwordx4
    uint4* d4 = (uint4*)bm;
    const uint4* s4 = (const uint4*)g_bits;
#pragma unroll
    for (int kk = 0; kk < 4; ++kk) d4[tid + kk*512] = s4[tid + kk*512];
  }
  if (tid == 0) s_off = 0;
  __syncthreads();

  // Phase A: keep flags from LDS bitmap, stable local positions, stash
  int running = 0;
  for (int s = 0; s < EPB; s += 512){
    int e = base + s + tid;
    int u = ei[e], v = ei[NE + e];
    bool keep = ((bm[u >> 5] >> (u & 31)) & 1u) &&
                ((bm[v >> 5] >> (v & 31)) & 1u);
    unsigned long long m = __ballot(keep);
    if (lane == 0) wsum[wid] = __popcll(m);
    __syncthreads();
    int wbase = 0;
#pragma unroll
    for (int w2 = 0; w2 < 8; ++w2) if (w2 < wid) wbase += wsum[w2];
    int tot = 0;
#pragma unroll
    for (int w2 = 0; w2 < 8; ++w2) tot += wsum[w2];
    if (keep){
      int lp = running + wbase + __popcll(m & ltm);
      if (lp < STASH){
        int2 p; p.x = g_nodemap[u]; p.y = g_nodemap[v]; rc[lp] = p;
      }
    }
    running += tot;
    __syncthreads();
  }
  int myc = running;

  // Phase B: decoupled lookback (wave 0) — relaxed atomics only (R4-R11)
  if (b == 0){
    if (tid == 0)
      atomicExch(&g_state[0], FLG_INC | (unsigned long long)(uint32_t)myc);
  } else if (wid == 0){
    if (lane == 0)
      atomicExch(&g_state[b], FLG_AGG | (unsigned long long)(uint32_t)myc);
    int prev = 0, win = b - 1;
    bool done = false;
    while (!done){
      int idxl = win - lane;
      unsigned long long st = (idxl >= 0) ? atomicAdd(&g_state[idxl], 0ull)
                                          : FLG_INC;
      unsigned f = (unsigned)(st >> 62);
      unsigned long long readym = __ballot(f != 0u);
      unsigned long long incm   = __ballot(f == 2u);
      if (incm){
        int l0 = __ffsll((long long)incm) - 1;
        unsigned long long needm = (l0 == 63) ? ~0ull : ((1ull << (l0+1)) - 1ull);
        if ((readym & needm) == needm){
          int contrib = (lane <= l0) ? (int)(uint32_t)st : 0;
#pragma unroll
          for (int off = 32; off; off >>= 1)
            contrib += __shfl_down(contrib, off);
          if (lane == 0) prev += contrib;
          done = true;
        }
      } else if (readym == ~0ull){
        int contrib = (int)(uint32_t)st;
#pragma unroll
        for (int off = 32; off; off >>= 1)
          contrib += __shfl_down(contrib, off);
        if (lane == 0) prev += contrib;
        win -= 64;
      } else {
        __builtin_amdgcn_s_sleep(2);
      }
    }
    if (lane == 0){
      atomicExch(&g_state[b], FLG_INC | (unsigned long long)(uint32_t)(prev + myc));
      s_off = prev;
      if (b == NEBLK-1)
        out[OFF_NE] = bfr((float)(prev + myc));
    }
  }
  __syncthreads();
  int off = s_off;

  // Phase C: write kept edges from stash (coalesced)
  int lim = myc < STASH ? myc : STASH;
  for (int i = tid; i < lim; i += 512){
    int2 p = rc[i];
    out[OFF_EDGE + off + i]      = bfr((float)p.x);
    out[OFF_EDGE + NE + off + i] = bfr((float)p.y);
  }
  // Rare fallback: stash overflow -> recompute positions
  if (myc > STASH){
    running = 0;
    __syncthreads();
    for (int s = 0; s < EPB; s += 512){
      int e = base + s + tid;
      int u = ei[e], v = ei[NE + e];
      bool keep = ((bm[u >> 5] >> (u & 31)) & 1u) &&
                  ((bm[v >> 5] >> (v & 31)) & 1u);
      unsigned long long m = __ballot(keep);
      if (lane == 0) wsum[wid] = __popcll(m);
      __syncthreads();
      int wbase = 0;
#pragma unroll
      for (int w2 = 0; w2 < 8; ++w2) if (w2 < wid) wbase += wsum[w2];
      int tot = 0;
#pragma unroll
      for (int w2 = 0; w2 < 8; ++w2) tot += wsum[w2];
      if (keep){
        int lp = running + wbase + __popcll(m & ltm);
        if (lp >= STASH){
          out[OFF_EDGE + off + lp]      = bfr((float)g_nodemap[u]);
          out[OFF_EDGE + NE + off + lp] = bfr((float)g_nodemap[v]);
        }
      }
      running += tot;
      __syncthreads();
    }
  }

  // Tail drop-slice: block b fills [NE - dropoff - drops, NE - dropoff)
  // with -1 in both rows. Slices tile [T, NE) exactly; values identical.
  int drops = EPB - myc;
  int dropoff = base - off;
  int t0 = NE - dropoff - drops;
  for (int i = tid; i < drops; i += 512){
    out[OFF_EDGE + t0 + i]      = -1.0f;
    out[OFF_EDGE + NE + t0 + i] = -1.0f;
  }
}

extern "C" void kernel_launch(void* const* d_in, const int* in_sizes, int n_in,
                              void* d_out, int out_size, void* d_ws, size_t ws_size,
                              hipStream_t stream) {
  const float* x = (const float*)d_in[0];
  const float* w = (const float*)d_in[1];
  const int*   ei = (const int*)d_in[2];
  float* out = (float*)d_out;

  hipLaunchKernelGGL(k_scores, dim3(NTOTAL/16),   dim3(256), 0, stream, x, w);
  hipLaunchKernelGGL(k_topk,   dim3(NB),          dim3(512), 0, stream);
  hipLaunchKernelGGL(k2,       dim3(NEBLK + NGB), dim3(512), 0, stream, ei, x, out);
}